// Round 10
// baseline (308.271 us; speedup 1.0000x reference)
//
#include <hip/hip_runtime.h>
#include <math.h>

#define TT     2048
#define BKK    64
#define OBSD   64
#define NH     16
#define PDIM   64
#define NSTATE 64
#define DINN   1024
#define TB     (TT*BKK)   // 131072 rows
#define NC     32         // chunks over T
#define CL     64         // steps per chunk
#define DDS    40         // dd row stride (floats): dec[16]@0 | xw[16]@16 | ob@32 | pad

// ---------- DPP wave-64 sum (result valid in lane 63) ----------
template <int CTRL>
__device__ __forceinline__ float dpp_add(float x) {
    int y = __builtin_amdgcn_update_dpp(0, __float_as_int(x), CTRL, 0xF, 0xF, true);
    return x + __int_as_float(y);
}
__device__ __forceinline__ float wave_sum_lane63(float x) {
    x = dpp_add<0x111>(x);
    x = dpp_add<0x112>(x);
    x = dpp_add<0x114>(x);
    x = dpp_add<0x118>(x);
    x = dpp_add<0x142>(x);
    x = dpp_add<0x143>(x);
    return x;
}

__device__ __forceinline__ float softplusf(float z) {
    return (z > 20.f) ? z : log1pf(expf(z));
}

// load dec[16]|xw[16] from a dd row into statically-indexed register arrays
#define LOAD_DX(ptr, dd_, xx_)                                            \
    {                                                                     \
        const float4* _p = (const float4*)(ptr);                          \
        float4 a0 = _p[0], a1 = _p[1], a2 = _p[2], a3 = _p[3];            \
        float4 b0 = _p[4], b1 = _p[5], b2 = _p[6], b3 = _p[7];            \
        dd_[0]=a0.x; dd_[1]=a0.y; dd_[2]=a0.z; dd_[3]=a0.w;               \
        dd_[4]=a1.x; dd_[5]=a1.y; dd_[6]=a1.z; dd_[7]=a1.w;               \
        dd_[8]=a2.x; dd_[9]=a2.y; dd_[10]=a2.z; dd_[11]=a2.w;             \
        dd_[12]=a3.x; dd_[13]=a3.y; dd_[14]=a3.z; dd_[15]=a3.w;           \
        xx_[0]=b0.x; xx_[1]=b0.y; xx_[2]=b0.z; xx_[3]=b0.w;               \
        xx_[4]=b1.x; xx_[5]=b1.y; xx_[6]=b1.z; xx_[7]=b1.w;               \
        xx_[8]=b2.x; xx_[9]=b2.y; xx_[10]=b2.z; xx_[11]=b2.w;             \
        xx_[12]=b3.x; xx_[13]=b3.y; xx_[14]=b3.z; xx_[15]=b3.w;           \
    }

// ---------- init (8 blocks): Wproj[64][16] and g0[16][64] ----------
__global__ __launch_bounds__(256)
void init_proj2(const float* __restrict__ Win, const float* __restrict__ Wout,
                const float* __restrict__ initS,
                float* __restrict__ wproj, float* __restrict__ g0) {
    const int t = threadIdx.x;
    if (blockIdx.x < 4) {
        const int idx = blockIdx.x * 256 + t;      // 0..1023
        const int k = idx >> 4, h = idx & 15;
        float s = 0.f;
#pragma unroll 8
        for (int p = 0; p < PDIM; ++p)
            s = fmaf(Win[(size_t)k * DINN + h * 64 + p], Wout[h * 64 + p], s);
        wproj[idx] = s;   // [k][h]
    } else {
        const int idx = (blockIdx.x - 4) * 256 + t; // 0..1023
        const int h = idx >> 6, n = idx & 63;
        float s = 0.f;
#pragma unroll 8
        for (int p = 0; p < PDIM; ++p)
            s = fmaf(initS[h * PDIM * NSTATE + p * NSTATE + n], Wout[h * 64 + p], s);
        g0[idx] = s;      // [h][n]
    }
}

// ---------- prelude3: dd = {dec[16], xw[16], ob} per (t,b) row ----------
// wave = 8 rows; lane: h = lane&15, q = lane>>4 (k-quarter)
__global__ __launch_bounds__(256)
void prelude3(const float* __restrict__ obs, const float* __restrict__ reward,
              const float* __restrict__ Wdt, const float* __restrict__ dtb,
              const float* __restrict__ Alog, const float* __restrict__ Dv,
              const float* __restrict__ wproj, float* __restrict__ dd) {
    int gw = (blockIdx.x * 256 + threadIdx.x) >> 6;
    gw = __builtin_amdgcn_readfirstlane(gw);
    const int lane = threadIdx.x & 63;
    const int row0 = gw * 8;
    if (row0 >= TB) return;

    const int h = lane & 15;
    const int q = lane >> 4;

    const float wdt_h = Wdt[h];
    const float dtb_h = dtb[h];
    const float A_h   = -expf(Alog[h]);
    const float D_h   = Dv[h];
    float wpj[16];
#pragma unroll
    for (int j = 0; j < 16; ++j)
        wpj[j] = wproj[(q * 16 + j) * 16 + h];

#pragma unroll 1
    for (int r = 0; r < 8; ++r) {
        const int row = row0 + r;

        // w[h] partial over this lane's k-quarter
        const float4* oq = (const float4*)(obs + (size_t)row * OBSD + q * 16);
        float4 o0 = oq[0], o1 = oq[1], o2 = oq[2], o3 = oq[3];
        float wpart = 0.f;
        wpart = fmaf(o0.x, wpj[0],  wpart); wpart = fmaf(o0.y, wpj[1],  wpart);
        wpart = fmaf(o0.z, wpj[2],  wpart); wpart = fmaf(o0.w, wpj[3],  wpart);
        wpart = fmaf(o1.x, wpj[4],  wpart); wpart = fmaf(o1.y, wpj[5],  wpart);
        wpart = fmaf(o1.z, wpj[6],  wpart); wpart = fmaf(o1.w, wpj[7],  wpart);
        wpart = fmaf(o2.x, wpj[8],  wpart); wpart = fmaf(o2.y, wpj[9],  wpart);
        wpart = fmaf(o2.z, wpj[10], wpart); wpart = fmaf(o2.w, wpj[11], wpart);
        wpart = fmaf(o3.x, wpj[12], wpart); wpart = fmaf(o3.y, wpj[13], wpart);
        wpart = fmaf(o3.z, wpj[14], wpart); wpart = fmaf(o3.w, wpj[15], wpart);
        wpart += __shfl_xor(wpart, 16, 64);
        wpart += __shfl_xor(wpart, 32, 64);   // every lane: w[h]

        const float rew  = reward[row];
        const float dtv  = softplusf(fmaf(rew, wdt_h, dtb_h));
        const float decv = expf(dtv * A_h);
        const float xwv  = dtv * wpart;

        float* dr = dd + (size_t)row * DDS;
        if (q == 0) dr[h]      = decv;
        if (q == 1) dr[16 + h] = xwv;

        float dw = D_h * wpart;
        dw += __shfl_xor(dw, 1, 64);
        dw += __shfl_xor(dw, 2, 64);
        dw += __shfl_xor(dw, 4, 64);
        dw += __shfl_xor(dw, 8, 64);
        if (lane == 0) dr[32] = dw;   // obase
    }
}

// ---------- phase A: fused B-proj + zero-init chunk scan -> Send, Ptot ----------
__global__ __launch_bounds__(256)
void phaseA(const float* __restrict__ obs, const float* __restrict__ dd,
            const float* __restrict__ WB,
            float* __restrict__ Send, float* __restrict__ Ptot) {
    int w = blockIdx.x * 4 + (threadIdx.x >> 6);
    w = __builtin_amdgcn_readfirstlane(w);
    const int lane = threadIdx.x & 63;   // n
    const int b = w & 63;
    const int c = w >> 6;

    // register-held weight column WB[:, lane]
    float wb[64];
#pragma unroll
    for (int k = 0; k < 64; ++k) wb[k] = WB[k * 64 + lane];

    float g[16], Pc[16];
#pragma unroll
    for (int hh = 0; hh < 16; ++hh) { g[hh] = 0.f; Pc[hh] = 1.f; }

    const float* orow = obs + ((size_t)(c * CL) * BKK + b) * OBSD;  // uniform
    const float* dr   = dd  + ((size_t)(c * CL) * BKK + b) * DDS;

#pragma unroll 1
    for (int i = 0; i < CL; ++i) {
        float dec_[16], xw_[16];
        LOAD_DX(dr, dec_, xw_);

        // B[n] = obs_row . WB[:,n]  (uniform obs -> s_load; 4 split chains)
        float s0 = 0.f, s1 = 0.f, s2 = 0.f, s3 = 0.f;
#pragma unroll
        for (int k = 0; k < 64; k += 4) {
            s0 = fmaf(orow[k],     wb[k],     s0);
            s1 = fmaf(orow[k + 1], wb[k + 1], s1);
            s2 = fmaf(orow[k + 2], wb[k + 2], s2);
            s3 = fmaf(orow[k + 3], wb[k + 3], s3);
        }
        const float Bv = (s0 + s1) + (s2 + s3);

#pragma unroll
        for (int hh = 0; hh < 16; ++hh) {
            g[hh] = fmaf(g[hh], dec_[hh], xw_[hh] * Bv);
            Pc[hh] *= dec_[hh];
        }
        orow += (size_t)BKK * OBSD;
        dr   += (size_t)BKK * DDS;
    }

    const size_t base = ((size_t)c * BKK + b) * 16;
#pragma unroll
    for (int hh = 0; hh < 16; ++hh)
        Send[(base + hh) * 64 + lane] = g[hh];
    if (lane == 0) {
#pragma unroll
        for (int hh = 0; hh < 16; ++hh)
            Ptot[base + hh] = Pc[hh];
    }
}

// ---------- phase B: serial scan over NC chunk states (per b) ----------
__global__ __launch_bounds__(64)
void phaseB(const float* __restrict__ g0, const float* __restrict__ Send,
            const float* __restrict__ Ptot, float* __restrict__ gcbuf) {
    const int b    = blockIdx.x;
    const int lane = threadIdx.x;   // n

    float g[16];
#pragma unroll
    for (int hh = 0; hh < 16; ++hh)
        g[hh] = g0[hh * 64 + lane];

    float S_[16], P_[16];
    {
        const size_t base = (size_t)b * 16;
#pragma unroll
        for (int hh = 0; hh < 16; ++hh) S_[hh] = Send[(base + hh) * 64 + lane];
        const float4* pp = (const float4*)(Ptot + base);
        float4 a0 = pp[0], a1 = pp[1], a2 = pp[2], a3 = pp[3];
        P_[0]=a0.x; P_[1]=a0.y; P_[2]=a0.z; P_[3]=a0.w;
        P_[4]=a1.x; P_[5]=a1.y; P_[6]=a1.z; P_[7]=a1.w;
        P_[8]=a2.x; P_[9]=a2.y; P_[10]=a2.z; P_[11]=a2.w;
        P_[12]=a3.x; P_[13]=a3.y; P_[14]=a3.z; P_[15]=a3.w;
    }

#pragma unroll 1
    for (int c = 0; c < NC; ++c) {
        const size_t base = ((size_t)c * BKK + b) * 16;
        float Sn[16], Pn[16];
        if (c < NC - 1) {
            const size_t nb = ((size_t)(c + 1) * BKK + b) * 16;
#pragma unroll
            for (int hh = 0; hh < 16; ++hh) Sn[hh] = Send[(nb + hh) * 64 + lane];
            const float4* pp = (const float4*)(Ptot + nb);
            float4 a0 = pp[0], a1 = pp[1], a2 = pp[2], a3 = pp[3];
            Pn[0]=a0.x; Pn[1]=a0.y; Pn[2]=a0.z; Pn[3]=a0.w;
            Pn[4]=a1.x; Pn[5]=a1.y; Pn[6]=a1.z; Pn[7]=a1.w;
            Pn[8]=a2.x; Pn[9]=a2.y; Pn[10]=a2.z; Pn[11]=a2.w;
            Pn[12]=a3.x; Pn[13]=a3.y; Pn[14]=a3.z; Pn[15]=a3.w;
        }
#pragma unroll
        for (int hh = 0; hh < 16; ++hh)
            gcbuf[(base + hh) * 64 + lane] = g[hh];
        if (c < NC - 1) {
#pragma unroll
            for (int hh = 0; hh < 16; ++hh) {
                g[hh] = fmaf(P_[hh], g[hh], S_[hh]);
                P_[hh] = Pn[hh]; S_[hh] = Sn[hh];
            }
        }
    }
}

// ---------- phase C: fused B/C-proj + seeded chunk scan -> q AND logits ----------
__global__ __launch_bounds__(256)
void phaseC(const float* __restrict__ obs, const float* __restrict__ dd,
            const float* __restrict__ WB, const float* __restrict__ WC,
            const float* __restrict__ gcbuf, float* __restrict__ qout) {
    int w = blockIdx.x * 4 + (threadIdx.x >> 6);
    w = __builtin_amdgcn_readfirstlane(w);
    const int lane = threadIdx.x & 63;   // n
    const int b = w & 63;
    const int c = w >> 6;

    float wb[64], wc[64];
#pragma unroll
    for (int k = 0; k < 64; ++k) wb[k] = WB[k * 64 + lane];
#pragma unroll
    for (int k = 0; k < 64; ++k) wc[k] = WC[k * 64 + lane];

    const size_t sbase = ((size_t)c * BKK + b) * 16;
    float g[16];
#pragma unroll
    for (int hh = 0; hh < 16; ++hh)
        g[hh] = gcbuf[(sbase + hh) * 64 + lane];

    const float* orow = obs + ((size_t)(c * CL) * BKK + b) * OBSD;  // uniform
    const float* dr   = dd  + ((size_t)(c * CL) * BKK + b) * DDS;

#pragma unroll 1
    for (int i = 0; i < CL; ++i) {
        float dec_[16], xw_[16];
        LOAD_DX(dr, dec_, xw_);
        const float ob = dr[32];

        float s0 = 0.f, s1 = 0.f, s2 = 0.f, s3 = 0.f;   // B
        float t0 = 0.f, t1 = 0.f, t2 = 0.f, t3 = 0.f;   // C
#pragma unroll
        for (int k = 0; k < 64; k += 4) {
            const float a0 = orow[k], a1 = orow[k + 1], a2 = orow[k + 2], a3 = orow[k + 3];
            s0 = fmaf(a0, wb[k],     s0);
            s1 = fmaf(a1, wb[k + 1], s1);
            s2 = fmaf(a2, wb[k + 2], s2);
            s3 = fmaf(a3, wb[k + 3], s3);
            t0 = fmaf(a0, wc[k],     t0);
            t1 = fmaf(a1, wc[k + 1], t1);
            t2 = fmaf(a2, wc[k + 2], t2);
            t3 = fmaf(a3, wc[k + 3], t3);
        }
        const float Bv = (s0 + s1) + (s2 + s3);
        const float Cv = (t0 + t1) + (t2 + t3);

        float y = 0.f;
#pragma unroll
        for (int hh = 0; hh < 16; ++hh) {
            g[hh] = fmaf(g[hh], dec_[hh], xw_[hh] * Bv);
            y = fmaf(g[hh], Cv, y);
        }

        float tot = wave_sum_lane63(y);
        if (lane == 63) {
            const size_t idx = (size_t)(c * CL + i) * BKK + b;
            const float v = tot + ob;
            qout[idx]      = v;   // q
            qout[TB + idx] = v;   // logits
        }

        orow += (size_t)BKK * OBSD;
        dr   += (size_t)BKK * DDS;
    }
}

extern "C" void kernel_launch(void* const* d_in, const int* in_sizes, int n_in,
                              void* d_out, int out_size, void* d_ws, size_t ws_size,
                              hipStream_t stream) {
    const float* obs    = (const float*)d_in[0];
    const float* reward = (const float*)d_in[1];
    const float* Win    = (const float*)d_in[2];
    const float* WB     = (const float*)d_in[3];
    const float* WC     = (const float*)d_in[4];
    const float* Wdt    = (const float*)d_in[5];
    const float* dtb    = (const float*)d_in[6];
    const float* Alog   = (const float*)d_in[7];
    const float* Dv     = (const float*)d_in[8];
    const float* Wout   = (const float*)d_in[9];
    const float* initS  = (const float*)d_in[10];
    float* qout = (float*)d_out;

    // workspace: dd (21.0MB) | Send (8.4MB) | gcbuf (8.4MB) | Ptot (0.13MB) | wproj | g0
    const size_t n_dd = (size_t)TB * DDS;          // 5.24 M floats
    const size_t n_cs = (size_t)NC * BKK * 16 * 64; // 2.10 M floats
    const size_t n_pt = (size_t)NC * BKK * 16;      // 32 K floats

    float* dd    = (float*)d_ws;
    float* Send  = dd + n_dd;
    float* gcbuf = Send + n_cs;
    float* Ptot  = gcbuf + n_cs;
    float* wproj = Ptot + n_pt;
    float* g0    = wproj + 1024;
    // total ≈ 38 MB; harness-proven ws ≥ 103 MB

    init_proj2<<<dim3(8), dim3(256), 0, stream>>>(Win, Wout, initS, wproj, g0);
    prelude3<<<dim3(TB / 32), dim3(256), 0, stream>>>(obs, reward, Wdt, dtb,
                                                      Alog, Dv, wproj, dd);
    phaseA<<<dim3(512), dim3(256), 0, stream>>>(obs, dd, WB, Send, Ptot);
    phaseB<<<dim3(BKK), dim3(64), 0, stream>>>(g0, Send, Ptot, gcbuf);
    phaseC<<<dim3(512), dim3(256), 0, stream>>>(obs, dd, WB, WC, gcbuf, qout);
}

// Round 11
// 280.707 us; speedup vs baseline: 1.0982x; 1.0982x over previous
//
#include <hip/hip_runtime.h>
#include <math.h>

#define TT     2048
#define BKK    64
#define OBSD   64
#define NH     16
#define PDIM   64
#define NSTATE 64
#define DINN   1024
#define TB     (TT*BKK)   // 131072 rows
#define DDS    32         // dd row stride: dec[16]@0 | xw[16]@16
#define BCS    128        // BC row stride: B[64] | C[64]

// ---------- DPP wave-64 sum (result valid in lane 63) ----------
template <int CTRL>
__device__ __forceinline__ float dpp_add(float x) {
    int y = __builtin_amdgcn_update_dpp(0, __float_as_int(x), CTRL, 0xF, 0xF, true);
    return x + __int_as_float(y);
}
__device__ __forceinline__ float wave_sum_lane63(float x) {
    x = dpp_add<0x111>(x);
    x = dpp_add<0x112>(x);
    x = dpp_add<0x114>(x);
    x = dpp_add<0x118>(x);
    x = dpp_add<0x142>(x);
    x = dpp_add<0x143>(x);
    return x;
}

__device__ __forceinline__ float softplusf(float z) {
    return (z > 20.f) ? z : log1pf(expf(z));
}

#define LOAD_DX(ptr, dd_, xx_)                                            \
    {                                                                     \
        const float4* _p = (const float4*)(ptr);                          \
        float4 a0 = _p[0], a1 = _p[1], a2 = _p[2], a3 = _p[3];            \
        float4 b0 = _p[4], b1 = _p[5], b2 = _p[6], b3 = _p[7];            \
        dd_[0]=a0.x; dd_[1]=a0.y; dd_[2]=a0.z; dd_[3]=a0.w;               \
        dd_[4]=a1.x; dd_[5]=a1.y; dd_[6]=a1.z; dd_[7]=a1.w;               \
        dd_[8]=a2.x; dd_[9]=a2.y; dd_[10]=a2.z; dd_[11]=a2.w;             \
        dd_[12]=a3.x; dd_[13]=a3.y; dd_[14]=a3.z; dd_[15]=a3.w;           \
        xx_[0]=b0.x; xx_[1]=b0.y; xx_[2]=b0.z; xx_[3]=b0.w;               \
        xx_[4]=b1.x; xx_[5]=b1.y; xx_[6]=b1.z; xx_[7]=b1.w;               \
        xx_[8]=b2.x; xx_[9]=b2.y; xx_[10]=b2.z; xx_[11]=b2.w;             \
        xx_[12]=b3.x; xx_[13]=b3.y; xx_[14]=b3.z; xx_[15]=b3.w;           \
    }

// ---------- init (8 blocks): Wproj[64][16] and g0[16][64] ----------
__global__ __launch_bounds__(256)
void init_proj2(const float* __restrict__ Win, const float* __restrict__ Wout,
                const float* __restrict__ initS,
                float* __restrict__ wproj, float* __restrict__ g0) {
    const int t = threadIdx.x;
    if (blockIdx.x < 4) {
        const int idx = blockIdx.x * 256 + t;
        const int k = idx >> 4, h = idx & 15;
        float s = 0.f;
#pragma unroll 8
        for (int p = 0; p < PDIM; ++p)
            s = fmaf(Win[(size_t)k * DINN + h * 64 + p], Wout[h * 64 + p], s);
        wproj[idx] = s;   // [k][h]
    } else {
        const int idx = (blockIdx.x - 4) * 256 + t;
        const int h = idx >> 6, n = idx & 63;
        float s = 0.f;
#pragma unroll 8
        for (int p = 0; p < PDIM; ++p)
            s = fmaf(initS[h * PDIM * NSTATE + p * NSTATE + n], Wout[h * 64 + p], s);
        g0[idx] = s;      // [h][n]
    }
}

// ---------- bc_gemm: BC[row] = [obs@WB | obs@WC], LDS-tiled ----------
// block = 4 waves, 128 rows; lane = n; wave w owns rows [w*32, w*32+32)
__global__ __launch_bounds__(256)
void bc_gemm(const float* __restrict__ obs, const float* __restrict__ WB,
             const float* __restrict__ WC, float* __restrict__ BC) {
    __shared__ float tile[128 * OBSD];   // 32 KB

    const int t = threadIdx.x;
    const size_t r0 = (size_t)blockIdx.x * 128;

    // stage 128 rows: 2048 float4, linear, coalesced, conflict-free
    {
        const float4* src = (const float4*)(obs + r0 * OBSD);
        float4* dst = (float4*)tile;
#pragma unroll
        for (int i = 0; i < 8; ++i)
            dst[i * 256 + t] = src[i * 256 + t];
    }
    __syncthreads();

    const int lane = t & 63;
    const int w = __builtin_amdgcn_readfirstlane(t >> 6);

    // register-held weight columns (intentional ~150 VGPR)
    float wb[64], wc[64];
#pragma unroll
    for (int k = 0; k < 64; ++k) wb[k] = WB[k * 64 + lane];
#pragma unroll
    for (int k = 0; k < 64; ++k) wc[k] = WC[k * 64 + lane];

    const float* trow = tile + w * 32 * OBSD;
    float* brow = BC + (r0 + w * 32) * BCS;

#pragma unroll 1
    for (int r = 0; r < 32; ++r) {
        const float4* tr4 = (const float4*)(trow + r * OBSD);
        float s0 = 0.f, s1 = 0.f, s2 = 0.f, s3 = 0.f;
        float c0 = 0.f, c1 = 0.f, c2 = 0.f, c3 = 0.f;
#pragma unroll
        for (int kq = 0; kq < 16; ++kq) {
            const float4 o = tr4[kq];   // broadcast ds_read_b128
            const int k = kq * 4;
            s0 = fmaf(o.x, wb[k],     s0);  c0 = fmaf(o.x, wc[k],     c0);
            s1 = fmaf(o.y, wb[k + 1], s1);  c1 = fmaf(o.y, wc[k + 1], c1);
            s2 = fmaf(o.z, wb[k + 2], s2);  c2 = fmaf(o.z, wc[k + 2], c2);
            s3 = fmaf(o.w, wb[k + 3], s3);  c3 = fmaf(o.w, wc[k + 3], c3);
        }
        brow[lane]      = (s0 + s1) + (s2 + s3);
        brow[64 + lane] = (c0 + c1) + (c2 + c3);
        brow += BCS;
    }
}

// ---------- prelude3: dd = {dec[16], xw[16]}, obw = obase per (t,b) ----------
__global__ __launch_bounds__(256)
void prelude3(const float* __restrict__ obs, const float* __restrict__ reward,
              const float* __restrict__ Wdt, const float* __restrict__ dtb,
              const float* __restrict__ Alog, const float* __restrict__ Dv,
              const float* __restrict__ wproj, float* __restrict__ dd,
              float* __restrict__ obw) {
    int gw = (blockIdx.x * 256 + threadIdx.x) >> 6;
    gw = __builtin_amdgcn_readfirstlane(gw);
    const int lane = threadIdx.x & 63;
    const int row0 = gw * 8;
    if (row0 >= TB) return;

    const int h = lane & 15;
    const int q = lane >> 4;

    const float wdt_h = Wdt[h];
    const float dtb_h = dtb[h];
    const float A_h   = -expf(Alog[h]);
    const float D_h   = Dv[h];
    float wpj[16];
#pragma unroll
    for (int j = 0; j < 16; ++j)
        wpj[j] = wproj[(q * 16 + j) * 16 + h];

#pragma unroll 1
    for (int r = 0; r < 8; ++r) {
        const int row = row0 + r;

        const float4* oq = (const float4*)(obs + (size_t)row * OBSD + q * 16);
        float4 o0 = oq[0], o1 = oq[1], o2 = oq[2], o3 = oq[3];
        float wpart = 0.f;
        wpart = fmaf(o0.x, wpj[0],  wpart); wpart = fmaf(o0.y, wpj[1],  wpart);
        wpart = fmaf(o0.z, wpj[2],  wpart); wpart = fmaf(o0.w, wpj[3],  wpart);
        wpart = fmaf(o1.x, wpj[4],  wpart); wpart = fmaf(o1.y, wpj[5],  wpart);
        wpart = fmaf(o1.z, wpj[6],  wpart); wpart = fmaf(o1.w, wpj[7],  wpart);
        wpart = fmaf(o2.x, wpj[8],  wpart); wpart = fmaf(o2.y, wpj[9],  wpart);
        wpart = fmaf(o2.z, wpj[10], wpart); wpart = fmaf(o2.w, wpj[11], wpart);
        wpart = fmaf(o3.x, wpj[12], wpart); wpart = fmaf(o3.y, wpj[13], wpart);
        wpart = fmaf(o3.z, wpj[14], wpart); wpart = fmaf(o3.w, wpj[15], wpart);
        wpart += __shfl_xor(wpart, 16, 64);
        wpart += __shfl_xor(wpart, 32, 64);   // every lane: w[h]

        const float rew  = reward[row];
        const float dtv  = softplusf(fmaf(rew, wdt_h, dtb_h));
        const float decv = expf(dtv * A_h);
        const float xwv  = dtv * wpart;

        float* dr = dd + (size_t)row * DDS;
        if (q == 0) dr[h]      = decv;
        if (q == 1) dr[16 + h] = xwv;

        float dw = D_h * wpart;
        dw += __shfl_xor(dw, 1, 64);
        dw += __shfl_xor(dw, 2, 64);
        dw += __shfl_xor(dw, 4, 64);
        dw += __shfl_xor(dw, 8, 64);
        if (lane == 0) obw[row] = dw;
    }
}

// ---------- phase A: streamed zero-init chunk scan -> Send, Ptot ----------
template <int NCT>
__global__ __launch_bounds__(256)
void phaseA(const float* __restrict__ BC, const float* __restrict__ dd,
            float* __restrict__ Send, float* __restrict__ Ptot) {
    const int CLT = TT / NCT;
    int w = blockIdx.x * 4 + (threadIdx.x >> 6);
    w = __builtin_amdgcn_readfirstlane(w);
    const int lane = threadIdx.x & 63;   // n
    const int b = w & 63;
    const int c = w >> 6;

    const float* bp = BC + ((size_t)(c * CLT) * BKK + b) * BCS;
    const float* dr = dd + ((size_t)(c * CLT) * BKK + b) * DDS;

    float g[16], Pc[16];
#pragma unroll
    for (int hh = 0; hh < 16; ++hh) { g[hh] = 0.f; Pc[hh] = 1.f; }

    float Bv = bp[lane];
    float dec_[16], xw_[16];
    LOAD_DX(dr, dec_, xw_);

#pragma unroll 2
    for (int i = 0; i < CLT; ++i) {
        const float* bn = bp + (size_t)BKK * BCS;
        const float* dn = dr + (size_t)BKK * DDS;
        float Bn = 0.f;
        float decn_[16], xwn_[16];
        if (i < CLT - 1) {
            Bn = bn[lane];
            LOAD_DX(dn, decn_, xwn_);
        }
#pragma unroll
        for (int hh = 0; hh < 16; ++hh) {
            g[hh] = fmaf(g[hh], dec_[hh], xw_[hh] * Bv);
            Pc[hh] *= dec_[hh];
        }
        bp = bn; dr = dn; Bv = Bn;
        if (i < CLT - 1) {
#pragma unroll
            for (int hh = 0; hh < 16; ++hh) { dec_[hh] = decn_[hh]; xw_[hh] = xwn_[hh]; }
        }
    }

    const size_t base = ((size_t)c * BKK + b) * 16;
#pragma unroll
    for (int hh = 0; hh < 16; ++hh)
        Send[(base + hh) * 64 + lane] = g[hh];
    if (lane == 0) {
#pragma unroll
        for (int hh = 0; hh < 16; ++hh)
            Ptot[base + hh] = Pc[hh];
    }
}

// ---------- phase B: serial scan over NCT chunk states (per b) ----------
template <int NCT>
__global__ __launch_bounds__(64)
void phaseB(const float* __restrict__ g0, const float* __restrict__ Send,
            const float* __restrict__ Ptot, float* __restrict__ gcbuf) {
    const int b    = blockIdx.x;
    const int lane = threadIdx.x;   // n

    float g[16];
#pragma unroll
    for (int hh = 0; hh < 16; ++hh)
        g[hh] = g0[hh * 64 + lane];

    float S_[16], P_[16];
    {
        const size_t base = (size_t)b * 16;
#pragma unroll
        for (int hh = 0; hh < 16; ++hh) S_[hh] = Send[(base + hh) * 64 + lane];
        const float4* pp = (const float4*)(Ptot + base);
        float4 a0 = pp[0], a1 = pp[1], a2 = pp[2], a3 = pp[3];
        P_[0]=a0.x; P_[1]=a0.y; P_[2]=a0.z; P_[3]=a0.w;
        P_[4]=a1.x; P_[5]=a1.y; P_[6]=a1.z; P_[7]=a1.w;
        P_[8]=a2.x; P_[9]=a2.y; P_[10]=a2.z; P_[11]=a2.w;
        P_[12]=a3.x; P_[13]=a3.y; P_[14]=a3.z; P_[15]=a3.w;
    }

#pragma unroll 1
    for (int c = 0; c < NCT; ++c) {
        const size_t base = ((size_t)c * BKK + b) * 16;
        float Sn[16], Pn[16];
        if (c < NCT - 1) {
            const size_t nb = ((size_t)(c + 1) * BKK + b) * 16;
#pragma unroll
            for (int hh = 0; hh < 16; ++hh) Sn[hh] = Send[(nb + hh) * 64 + lane];
            const float4* pp = (const float4*)(Ptot + nb);
            float4 a0 = pp[0], a1 = pp[1], a2 = pp[2], a3 = pp[3];
            Pn[0]=a0.x; Pn[1]=a0.y; Pn[2]=a0.z; Pn[3]=a0.w;
            Pn[4]=a1.x; Pn[5]=a1.y; Pn[6]=a1.z; Pn[7]=a1.w;
            Pn[8]=a2.x; Pn[9]=a2.y; Pn[10]=a2.z; Pn[11]=a2.w;
            Pn[12]=a3.x; Pn[13]=a3.y; Pn[14]=a3.z; Pn[15]=a3.w;
        }
#pragma unroll
        for (int hh = 0; hh < 16; ++hh)
            gcbuf[(base + hh) * 64 + lane] = g[hh];
        if (c < NCT - 1) {
#pragma unroll
            for (int hh = 0; hh < 16; ++hh) {
                g[hh] = fmaf(P_[hh], g[hh], S_[hh]);
                P_[hh] = Pn[hh]; S_[hh] = Sn[hh];
            }
        }
    }
}

// ---------- phase C: streamed seeded chunk scan -> q AND logits ----------
template <int NCT>
__global__ __launch_bounds__(256)
void phaseC(const float* __restrict__ BC, const float* __restrict__ dd,
            const float* __restrict__ obw, const float* __restrict__ gcbuf,
            float* __restrict__ qout) {
    const int CLT = TT / NCT;
    int w = blockIdx.x * 4 + (threadIdx.x >> 6);
    w = __builtin_amdgcn_readfirstlane(w);
    const int lane = threadIdx.x & 63;   // n
    const int b = w & 63;
    const int c = w >> 6;

    const size_t sbase = ((size_t)c * BKK + b) * 16;
    float g[16];
#pragma unroll
    for (int hh = 0; hh < 16; ++hh)
        g[hh] = gcbuf[(sbase + hh) * 64 + lane];

    const float* bp = BC  + ((size_t)(c * CLT) * BKK + b) * BCS;
    const float* dr = dd  + ((size_t)(c * CLT) * BKK + b) * DDS;
    const float* op = obw + ((size_t)(c * CLT) * BKK + b);

    float Bv = bp[lane];
    float Cv = bp[64 + lane];
    float ob = op[0];
    float dec_[16], xw_[16];
    LOAD_DX(dr, dec_, xw_);

#pragma unroll 2
    for (int i = 0; i < CLT; ++i) {
        const float* bn = bp + (size_t)BKK * BCS;
        const float* dn = dr + (size_t)BKK * DDS;
        const float* on = op + (size_t)BKK;
        float Bn = 0.f, Cn = 0.f, obn = 0.f;
        float decn_[16], xwn_[16];
        if (i < CLT - 1) {
            Bn = bn[lane]; Cn = bn[64 + lane]; obn = on[0];
            LOAD_DX(dn, decn_, xwn_);
        }

        float y = 0.f;
#pragma unroll
        for (int hh = 0; hh < 16; ++hh) {
            g[hh] = fmaf(g[hh], dec_[hh], xw_[hh] * Bv);
            y = fmaf(g[hh], Cv, y);
        }

        float tot = wave_sum_lane63(y);
        if (lane == 63) {
            const size_t idx = (size_t)(c * CLT + i) * BKK + b;
            const float v = tot + ob;
            qout[idx]      = v;   // q
            qout[TB + idx] = v;   // logits
        }

        bp = bn; dr = dn; op = on;
        Bv = Bn; Cv = Cn; ob = obn;
        if (i < CLT - 1) {
#pragma unroll
            for (int hh = 0; hh < 16; ++hh) { dec_[hh] = decn_[hh]; xw_[hh] = xwn_[hh]; }
        }
    }
}

extern "C" void kernel_launch(void* const* d_in, const int* in_sizes, int n_in,
                              void* d_out, int out_size, void* d_ws, size_t ws_size,
                              hipStream_t stream) {
    const float* obs    = (const float*)d_in[0];
    const float* reward = (const float*)d_in[1];
    const float* Win    = (const float*)d_in[2];
    const float* WB     = (const float*)d_in[3];
    const float* WC     = (const float*)d_in[4];
    const float* Wdt    = (const float*)d_in[5];
    const float* dtb    = (const float*)d_in[6];
    const float* Alog   = (const float*)d_in[7];
    const float* Dv     = (const float*)d_in[8];
    const float* Wout   = (const float*)d_in[9];
    const float* initS  = (const float*)d_in[10];
    float* qout = (float*)d_out;

    const size_t n_bc = (size_t)TB * BCS;   // 16.78 M floats (67.1 MB)
    const size_t n_dd = (size_t)TB * DDS;   //  4.19 M floats (16.8 MB)
    const size_t n_ob = (size_t)TB;         //  0.13 M floats ( 0.5 MB)

    float* BC    = (float*)d_ws;
    float* dd    = BC + n_bc;
    float* obw   = dd + n_dd;
    float* wproj = obw + n_ob;
    float* g0    = wproj + 1024;
    float* Send  = g0 + 1024;

    const size_t n_cs64 = (size_t)64 * BKK * 16 * 64;
    const size_t n_pt64 = (size_t)64 * BKK * 16;
    const size_t need64 = (n_bc + n_dd + n_ob + 2048 + 2 * n_cs64 + n_pt64) * 4; // ~118.3 MB

    init_proj2<<<dim3(8), dim3(256), 0, stream>>>(Win, Wout, initS, wproj, g0);
    bc_gemm<<<dim3(TB / 128), dim3(256), 0, stream>>>(obs, WB, WC, BC);
    prelude3<<<dim3(TB / 32), dim3(256), 0, stream>>>(obs, reward, Wdt, dtb,
                                                      Alog, Dv, wproj, dd, obw);

    if (ws_size >= need64) {
        float* gcbuf = Send + n_cs64;
        float* Ptot  = gcbuf + n_cs64;
        phaseA<64><<<dim3(64 * 16), dim3(256), 0, stream>>>(BC, dd, Send, Ptot);
        phaseB<64><<<dim3(BKK), dim3(64), 0, stream>>>(g0, Send, Ptot, gcbuf);
        phaseC<64><<<dim3(64 * 16), dim3(256), 0, stream>>>(BC, dd, obw, gcbuf, qout);
    } else {
        const size_t n_cs32 = (size_t)32 * BKK * 16 * 64;
        float* gcbuf = Send + n_cs32;
        float* Ptot  = gcbuf + n_cs32;
        phaseA<32><<<dim3(32 * 16), dim3(256), 0, stream>>>(BC, dd, Send, Ptot);
        phaseB<32><<<dim3(BKK), dim3(64), 0, stream>>>(g0, Send, Ptot, gcbuf);
        phaseC<32><<<dim3(32 * 16), dim3(256), 0, stream>>>(BC, dd, obw, gcbuf, qout);
    }
}

// Round 12
// 255.136 us; speedup vs baseline: 1.2083x; 1.1002x over previous
//
#include <hip/hip_runtime.h>
#include <math.h>

#define TT     2048
#define BKK    64
#define OBSD   64
#define NH     16
#define PDIM   64
#define NSTATE 64
#define DINN   1024
#define TB     (TT*BKK)   // 131072 rows
#define DDS    32         // dd row stride: dec[16]@0 | xw[16]@16

// ---------- DPP wave-64 sum (result valid in lane 63) ----------
template <int CTRL>
__device__ __forceinline__ float dpp_add(float x) {
    int y = __builtin_amdgcn_update_dpp(0, __float_as_int(x), CTRL, 0xF, 0xF, true);
    return x + __int_as_float(y);
}
__device__ __forceinline__ float wave_sum_lane63(float x) {
    x = dpp_add<0x111>(x);
    x = dpp_add<0x112>(x);
    x = dpp_add<0x114>(x);
    x = dpp_add<0x118>(x);
    x = dpp_add<0x142>(x);
    x = dpp_add<0x143>(x);
    return x;
}

__device__ __forceinline__ float softplusf(float z) {
    return (z > 20.f) ? z : log1pf(expf(z));
}

#define LOAD_DX(ptr, dd_, xx_)                                            \
    {                                                                     \
        const float4* _p = (const float4*)(ptr);                          \
        float4 a0 = _p[0], a1 = _p[1], a2 = _p[2], a3 = _p[3];            \
        float4 b0 = _p[4], b1 = _p[5], b2 = _p[6], b3 = _p[7];            \
        dd_[0]=a0.x; dd_[1]=a0.y; dd_[2]=a0.z; dd_[3]=a0.w;               \
        dd_[4]=a1.x; dd_[5]=a1.y; dd_[6]=a1.z; dd_[7]=a1.w;               \
        dd_[8]=a2.x; dd_[9]=a2.y; dd_[10]=a2.z; dd_[11]=a2.w;             \
        dd_[12]=a3.x; dd_[13]=a3.y; dd_[14]=a3.z; dd_[15]=a3.w;           \
        xx_[0]=b0.x; xx_[1]=b0.y; xx_[2]=b0.z; xx_[3]=b0.w;               \
        xx_[4]=b1.x; xx_[5]=b1.y; xx_[6]=b1.z; xx_[7]=b1.w;               \
        xx_[8]=b2.x; xx_[9]=b2.y; xx_[10]=b2.z; xx_[11]=b2.w;             \
        xx_[12]=b3.x; xx_[13]=b3.y; xx_[14]=b3.z; xx_[15]=b3.w;           \
    }

// ---------- init (8 blocks): Wproj[64][16] and g0[16][64] ----------
__global__ __launch_bounds__(256)
void init_proj2(const float* __restrict__ Win, const float* __restrict__ Wout,
                const float* __restrict__ initS,
                float* __restrict__ wproj, float* __restrict__ g0) {
    const int t = threadIdx.x;
    if (blockIdx.x < 4) {
        const int idx = blockIdx.x * 256 + t;
        const int k = idx >> 4, h = idx & 15;
        float s = 0.f;
#pragma unroll 8
        for (int p = 0; p < PDIM; ++p)
            s = fmaf(Win[(size_t)k * DINN + h * 64 + p], Wout[h * 64 + p], s);
        wproj[idx] = s;   // [k][h]
    } else {
        const int idx = (blockIdx.x - 4) * 256 + t;
        const int h = idx >> 6, n = idx & 63;
        float s = 0.f;
#pragma unroll 8
        for (int p = 0; p < PDIM; ++p)
            s = fmaf(initS[h * PDIM * NSTATE + p * NSTATE + n], Wout[h * 64 + p], s);
        g0[idx] = s;      // [h][n]
    }
}

// ---------- proj_all: one obs read -> Bws, Cws, dd, obw ----------
// block = 4 waves, 64-row LDS tile; wave w owns rows [w*16, w*16+16)
// main pass: k-blocked (32 weight regs live), lane = n
// w/dd pass: lane = (q,h), tile re-read broadcast
__global__ __launch_bounds__(256, 4)
void proj_all(const float* __restrict__ obs, const float* __restrict__ reward,
              const float* __restrict__ WB, const float* __restrict__ WC,
              const float* __restrict__ Wdt, const float* __restrict__ dtb,
              const float* __restrict__ Alog, const float* __restrict__ Dv,
              const float* __restrict__ wproj,
              float* __restrict__ Bws, float* __restrict__ Cws,
              float* __restrict__ dd, float* __restrict__ obw) {
    __shared__ float tile[64 * OBSD];   // 16 KB

    const int t = threadIdx.x;
    const size_t r0 = (size_t)blockIdx.x * 64;

    // stage 64 rows: 1024 float4, linear, coalesced, conflict-free
    {
        const float4* src = (const float4*)(obs + r0 * OBSD);
        float4* dst = (float4*)tile;
#pragma unroll
        for (int i = 0; i < 4; ++i)
            dst[i * 256 + t] = src[i * 256 + t];
    }
    __syncthreads();

    const int lane = t & 63;
    const int w = __builtin_amdgcn_readfirstlane(t >> 6);
    const int rw = w * 16;               // wave's first row in tile

    // ---- main pass: B, C for 16 rows ----
    float accB[16], accC[16];
#pragma unroll
    for (int r = 0; r < 16; ++r) { accB[r] = 0.f; accC[r] = 0.f; }

#pragma unroll 1
    for (int kb = 0; kb < 4; ++kb) {
        float wb[16], wc[16];
#pragma unroll
        for (int j = 0; j < 16; ++j) {
            wb[j] = WB[(kb * 16 + j) * 64 + lane];   // coalesced, L1-hot
            wc[j] = WC[(kb * 16 + j) * 64 + lane];
        }
#pragma unroll
        for (int r = 0; r < 16; ++r) {
            const float4* tp = (const float4*)(tile + (rw + r) * OBSD + kb * 16);
            const float4 o0 = tp[0], o1 = tp[1], o2 = tp[2], o3 = tp[3];  // broadcast
            accB[r] = fmaf(o0.x, wb[0],  accB[r]);  accC[r] = fmaf(o0.x, wc[0],  accC[r]);
            accB[r] = fmaf(o0.y, wb[1],  accB[r]);  accC[r] = fmaf(o0.y, wc[1],  accC[r]);
            accB[r] = fmaf(o0.z, wb[2],  accB[r]);  accC[r] = fmaf(o0.z, wc[2],  accC[r]);
            accB[r] = fmaf(o0.w, wb[3],  accB[r]);  accC[r] = fmaf(o0.w, wc[3],  accC[r]);
            accB[r] = fmaf(o1.x, wb[4],  accB[r]);  accC[r] = fmaf(o1.x, wc[4],  accC[r]);
            accB[r] = fmaf(o1.y, wb[5],  accB[r]);  accC[r] = fmaf(o1.y, wc[5],  accC[r]);
            accB[r] = fmaf(o1.z, wb[6],  accB[r]);  accC[r] = fmaf(o1.z, wc[6],  accC[r]);
            accB[r] = fmaf(o1.w, wb[7],  accB[r]);  accC[r] = fmaf(o1.w, wc[7],  accC[r]);
            accB[r] = fmaf(o2.x, wb[8],  accB[r]);  accC[r] = fmaf(o2.x, wc[8],  accC[r]);
            accB[r] = fmaf(o2.y, wb[9],  accB[r]);  accC[r] = fmaf(o2.y, wc[9],  accC[r]);
            accB[r] = fmaf(o2.z, wb[10], accB[r]);  accC[r] = fmaf(o2.z, wc[10], accC[r]);
            accB[r] = fmaf(o2.w, wb[11], accB[r]);  accC[r] = fmaf(o2.w, wc[11], accC[r]);
            accB[r] = fmaf(o3.x, wb[12], accB[r]);  accC[r] = fmaf(o3.x, wc[12], accC[r]);
            accB[r] = fmaf(o3.y, wb[13], accB[r]);  accC[r] = fmaf(o3.y, wc[13], accC[r]);
            accB[r] = fmaf(o3.z, wb[14], accB[r]);  accC[r] = fmaf(o3.z, wc[14], accC[r]);
            accB[r] = fmaf(o3.w, wb[15], accB[r]);  accC[r] = fmaf(o3.w, wc[15], accC[r]);
        }
    }
#pragma unroll
    for (int r = 0; r < 16; ++r) {
        Bws[(r0 + rw + r) * 64 + lane] = accB[r];
        Cws[(r0 + rw + r) * 64 + lane] = accC[r];
    }

    // ---- w/dd pass: lane = (q,h) ----
    const int h = lane & 15;
    const int q = lane >> 4;
    const float wdt_h = Wdt[h];
    const float dtb_h = dtb[h];
    const float A_h   = -expf(Alog[h]);
    const float D_h   = Dv[h];
    float wpj[16];
#pragma unroll
    for (int j = 0; j < 16; ++j)
        wpj[j] = wproj[(q * 16 + j) * 16 + h];

#pragma unroll 1
    for (int r = 0; r < 16; ++r) {
        const size_t row = r0 + rw + r;
        const float4* tp = (const float4*)(tile + (rw + r) * OBSD + q * 16);
        const float4 o0 = tp[0], o1 = tp[1], o2 = tp[2], o3 = tp[3];
        float wpart = 0.f;
        wpart = fmaf(o0.x, wpj[0],  wpart); wpart = fmaf(o0.y, wpj[1],  wpart);
        wpart = fmaf(o0.z, wpj[2],  wpart); wpart = fmaf(o0.w, wpj[3],  wpart);
        wpart = fmaf(o1.x, wpj[4],  wpart); wpart = fmaf(o1.y, wpj[5],  wpart);
        wpart = fmaf(o1.z, wpj[6],  wpart); wpart = fmaf(o1.w, wpj[7],  wpart);
        wpart = fmaf(o2.x, wpj[8],  wpart); wpart = fmaf(o2.y, wpj[9],  wpart);
        wpart = fmaf(o2.z, wpj[10], wpart); wpart = fmaf(o2.w, wpj[11], wpart);
        wpart = fmaf(o3.x, wpj[12], wpart); wpart = fmaf(o3.y, wpj[13], wpart);
        wpart = fmaf(o3.z, wpj[14], wpart); wpart = fmaf(o3.w, wpj[15], wpart);
        wpart += __shfl_xor(wpart, 16, 64);
        wpart += __shfl_xor(wpart, 32, 64);   // all lanes: w[h]

        const float rew  = reward[row];       // uniform s_load
        const float dtv  = softplusf(fmaf(rew, wdt_h, dtb_h));
        const float decv = expf(dtv * A_h);
        const float xwv  = dtv * wpart;

        float* dr = dd + row * DDS;
        if (q == 0) dr[h]      = decv;
        if (q == 1) dr[16 + h] = xwv;

        float dw = D_h * wpart;
        dw += __shfl_xor(dw, 1, 64);
        dw += __shfl_xor(dw, 2, 64);
        dw += __shfl_xor(dw, 4, 64);
        dw += __shfl_xor(dw, 8, 64);
        if (lane == 0) obw[row] = dw;
    }
}

// ---------- phase A: streamed zero-init chunk scan -> Send, Ptot ----------
template <int NCT>
__global__ __launch_bounds__(256)
void phaseA(const float* __restrict__ Bws, const float* __restrict__ dd,
            float* __restrict__ Send, float* __restrict__ Ptot) {
    const int CLT = TT / NCT;
    int w = blockIdx.x * 4 + (threadIdx.x >> 6);
    w = __builtin_amdgcn_readfirstlane(w);
    const int lane = threadIdx.x & 63;   // n
    const int b = w & 63;
    const int c = w >> 6;

    const float* bp = Bws + ((size_t)(c * CLT) * BKK + b) * 64;
    const float* dr = dd  + ((size_t)(c * CLT) * BKK + b) * DDS;

    float g[16], Pc[16];
#pragma unroll
    for (int hh = 0; hh < 16; ++hh) { g[hh] = 0.f; Pc[hh] = 1.f; }

    float Bv = bp[lane];
    float dec_[16], xw_[16];
    LOAD_DX(dr, dec_, xw_);

#pragma unroll 2
    for (int i = 0; i < CLT; ++i) {
        const float* bn = bp + (size_t)BKK * 64;
        const float* dn = dr + (size_t)BKK * DDS;
        float Bn = 0.f;
        float decn_[16], xwn_[16];
        if (i < CLT - 1) {
            Bn = bn[lane];
            LOAD_DX(dn, decn_, xwn_);
        }
#pragma unroll
        for (int hh = 0; hh < 16; ++hh) {
            g[hh] = fmaf(g[hh], dec_[hh], xw_[hh] * Bv);
            Pc[hh] *= dec_[hh];
        }
        bp = bn; dr = dn; Bv = Bn;
        if (i < CLT - 1) {
#pragma unroll
            for (int hh = 0; hh < 16; ++hh) { dec_[hh] = decn_[hh]; xw_[hh] = xwn_[hh]; }
        }
    }

    const size_t base = ((size_t)c * BKK + b) * 16;
#pragma unroll
    for (int hh = 0; hh < 16; ++hh)
        Send[(base + hh) * 64 + lane] = g[hh];
    if (lane == 0) {
#pragma unroll
        for (int hh = 0; hh < 16; ++hh)
            Ptot[base + hh] = Pc[hh];
    }
}

// ---------- phase B: serial scan over NCT chunk states (per b) ----------
template <int NCT>
__global__ __launch_bounds__(64)
void phaseB(const float* __restrict__ g0, const float* __restrict__ Send,
            const float* __restrict__ Ptot, float* __restrict__ gcbuf) {
    const int b    = blockIdx.x;
    const int lane = threadIdx.x;   // n

    float g[16];
#pragma unroll
    for (int hh = 0; hh < 16; ++hh)
        g[hh] = g0[hh * 64 + lane];

    float S_[16], P_[16];
    {
        const size_t base = (size_t)b * 16;
#pragma unroll
        for (int hh = 0; hh < 16; ++hh) S_[hh] = Send[(base + hh) * 64 + lane];
        const float4* pp = (const float4*)(Ptot + base);
        float4 a0 = pp[0], a1 = pp[1], a2 = pp[2], a3 = pp[3];
        P_[0]=a0.x; P_[1]=a0.y; P_[2]=a0.z; P_[3]=a0.w;
        P_[4]=a1.x; P_[5]=a1.y; P_[6]=a1.z; P_[7]=a1.w;
        P_[8]=a2.x; P_[9]=a2.y; P_[10]=a2.z; P_[11]=a2.w;
        P_[12]=a3.x; P_[13]=a3.y; P_[14]=a3.z; P_[15]=a3.w;
    }

#pragma unroll 1
    for (int c = 0; c < NCT; ++c) {
        const size_t base = ((size_t)c * BKK + b) * 16;
        float Sn[16], Pn[16];
        if (c < NCT - 1) {
            const size_t nb = ((size_t)(c + 1) * BKK + b) * 16;
#pragma unroll
            for (int hh = 0; hh < 16; ++hh) Sn[hh] = Send[(nb + hh) * 64 + lane];
            const float4* pp = (const float4*)(Ptot + nb);
            float4 a0 = pp[0], a1 = pp[1], a2 = pp[2], a3 = pp[3];
            Pn[0]=a0.x; Pn[1]=a0.y; Pn[2]=a0.z; Pn[3]=a0.w;
            Pn[4]=a1.x; Pn[5]=a1.y; Pn[6]=a1.z; Pn[7]=a1.w;
            Pn[8]=a2.x; Pn[9]=a2.y; Pn[10]=a2.z; Pn[11]=a2.w;
            Pn[12]=a3.x; Pn[13]=a3.y; Pn[14]=a3.z; Pn[15]=a3.w;
        }
#pragma unroll
        for (int hh = 0; hh < 16; ++hh)
            gcbuf[(base + hh) * 64 + lane] = g[hh];
        if (c < NCT - 1) {
#pragma unroll
            for (int hh = 0; hh < 16; ++hh) {
                g[hh] = fmaf(P_[hh], g[hh], S_[hh]);
                P_[hh] = Pn[hh]; S_[hh] = Sn[hh];
            }
        }
    }
}

// ---------- phase C: streamed seeded chunk scan -> q AND logits ----------
template <int NCT>
__global__ __launch_bounds__(256)
void phaseC(const float* __restrict__ Bws, const float* __restrict__ Cws,
            const float* __restrict__ dd, const float* __restrict__ obw,
            const float* __restrict__ gcbuf, float* __restrict__ qout) {
    const int CLT = TT / NCT;
    int w = blockIdx.x * 4 + (threadIdx.x >> 6);
    w = __builtin_amdgcn_readfirstlane(w);
    const int lane = threadIdx.x & 63;   // n
    const int b = w & 63;
    const int c = w >> 6;

    const size_t sbase = ((size_t)c * BKK + b) * 16;
    float g[16];
#pragma unroll
    for (int hh = 0; hh < 16; ++hh)
        g[hh] = gcbuf[(sbase + hh) * 64 + lane];

    const float* bp = Bws + ((size_t)(c * CLT) * BKK + b) * 64;
    const float* cp = Cws + ((size_t)(c * CLT) * BKK + b) * 64;
    const float* dr = dd  + ((size_t)(c * CLT) * BKK + b) * DDS;
    const float* op = obw + ((size_t)(c * CLT) * BKK + b);

    float Bv = bp[lane];
    float Cv = cp[lane];
    float ob = op[0];
    float dec_[16], xw_[16];
    LOAD_DX(dr, dec_, xw_);

#pragma unroll 2
    for (int i = 0; i < CLT; ++i) {
        const float* bn = bp + (size_t)BKK * 64;
        const float* cn = cp + (size_t)BKK * 64;
        const float* dn = dr + (size_t)BKK * DDS;
        const float* on = op + (size_t)BKK;
        float Bn = 0.f, Cn = 0.f, obn = 0.f;
        float decn_[16], xwn_[16];
        if (i < CLT - 1) {
            Bn = bn[lane]; Cn = cn[lane]; obn = on[0];
            LOAD_DX(dn, decn_, xwn_);
        }

        float y = 0.f;
#pragma unroll
        for (int hh = 0; hh < 16; ++hh) {
            g[hh] = fmaf(g[hh], dec_[hh], xw_[hh] * Bv);
            y = fmaf(g[hh], Cv, y);
        }

        float tot = wave_sum_lane63(y);
        if (lane == 63) {
            const size_t idx = (size_t)(c * CLT + i) * BKK + b;
            const float v = tot + ob;
            qout[idx]      = v;   // q
            qout[TB + idx] = v;   // logits
        }

        bp = bn; cp = cn; dr = dn; op = on;
        Bv = Bn; Cv = Cn; ob = obn;
        if (i < CLT - 1) {
#pragma unroll
            for (int hh = 0; hh < 16; ++hh) { dec_[hh] = decn_[hh]; xw_[hh] = xwn_[hh]; }
        }
    }
}

extern "C" void kernel_launch(void* const* d_in, const int* in_sizes, int n_in,
                              void* d_out, int out_size, void* d_ws, size_t ws_size,
                              hipStream_t stream) {
    const float* obs    = (const float*)d_in[0];
    const float* reward = (const float*)d_in[1];
    const float* Win    = (const float*)d_in[2];
    const float* WB     = (const float*)d_in[3];
    const float* WC     = (const float*)d_in[4];
    const float* Wdt    = (const float*)d_in[5];
    const float* dtb    = (const float*)d_in[6];
    const float* Alog   = (const float*)d_in[7];
    const float* Dv     = (const float*)d_in[8];
    const float* Wout   = (const float*)d_in[9];
    const float* initS  = (const float*)d_in[10];
    float* qout = (float*)d_out;

    const size_t n_B  = (size_t)TB * 64;   // 8.39 M floats each (33.5 MB)
    const size_t n_dd = (size_t)TB * DDS;  // 4.19 M floats (16.8 MB)
    const size_t n_ob = (size_t)TB;        // 0.5 MB

    float* Bws   = (float*)d_ws;
    float* Cws   = Bws + n_B;
    float* dd    = Cws + n_B;
    float* obw   = dd + n_dd;
    float* wproj = obw + n_ob;
    float* g0    = wproj + 1024;
    float* Send  = g0 + 1024;

    const size_t n_cs64 = (size_t)64 * BKK * 16 * 64;   // 4.19 M floats
    const size_t n_pt64 = (size_t)64 * BKK * 16;
    const size_t need64 = (2 * n_B + n_dd + n_ob + 2048 + 2 * n_cs64 + n_pt64) * 4; // ~118.2 MB

    init_proj2<<<dim3(8), dim3(256), 0, stream>>>(Win, Wout, initS, wproj, g0);
    proj_all<<<dim3(TB / 64), dim3(256), 0, stream>>>(obs, reward, WB, WC, Wdt, dtb,
                                                      Alog, Dv, wproj, Bws, Cws, dd, obw);

    if (ws_size >= need64) {
        float* gcbuf = Send + n_cs64;
        float* Ptot  = gcbuf + n_cs64;
        phaseA<64><<<dim3(64 * 16), dim3(256), 0, stream>>>(Bws, dd, Send, Ptot);
        phaseB<64><<<dim3(BKK), dim3(64), 0, stream>>>(g0, Send, Ptot, gcbuf);
        phaseC<64><<<dim3(64 * 16), dim3(256), 0, stream>>>(Bws, Cws, dd, obw, gcbuf, qout);
    } else {
        // NC=32 tier: ~101.2 MB (< R8-proven 102.9 MB)
        const size_t n_cs32 = (size_t)32 * BKK * 16 * 64;
        float* gcbuf = Send + n_cs32;
        float* Ptot  = gcbuf + n_cs32;
        phaseA<32><<<dim3(32 * 16), dim3(256), 0, stream>>>(Bws, dd, Send, Ptot);
        phaseB<32><<<dim3(BKK), dim3(64), 0, stream>>>(g0, Send, Ptot, gcbuf);
        phaseC<32><<<dim3(32 * 16), dim3(256), 0, stream>>>(Bws, Cws, dd, obw, gcbuf, qout);
    }
}